// Round 4
// baseline (373.440 us; speedup 1.0000x reference)
//
#include <hip/hip_runtime.h>
#include <float.h>

// Disable FP contraction file-wide: IoU/encode/threshold compares must match
// numpy bit patterns; none of the hot loops are FMA-throughput-bound.
#pragma clang fp contract(off)

typedef unsigned long long ull;
typedef unsigned int u32;

#define THRESH 0.5f
#define PPT 4          // priors per thread in match phase
#define SEL_T 512      // threads in k_select
#define ENC_SEG 1024   // priors per k_encode_ce block
#define LSE_ROWS 128   // conf rows per k_lse block (tile = 128*324B = 41472B)

// ---------------------------------------------------------------- helpers

__device__ __forceinline__ float sl1(float d) {
    float a = fabsf(d);
    return (a < 1.f) ? 0.5f * d * d : a - 0.5f;
}

__device__ __forceinline__ void gload16(const void* g, void* l) {
    __builtin_amdgcn_global_load_lds(
        (const __attribute__((address_space(1))) void*)g,
        (__attribute__((address_space(3))) void*)l, 16, 0, 0);
}
__device__ __forceinline__ void gload4(const void* g, void* l) {
    __builtin_amdgcn_global_load_lds(
        (const __attribute__((address_space(1))) void*)g,
        (__attribute__((address_space(3))) void*)l, 4, 0, 0);
}

// ---------------------------------------------------------------- K1a: logsumexp over conf rows
// One block = 128 consecutive rows = 41472 B contiguous tile, staged to LDS
// via global_load_lds width-16 (coalesced, no VGPR round-trip, linear LDS):
// 40 x 1KB chunks (10 per wave) + 2 x 256B tails. Then 2 threads/row sum
// halves serially (elems 0..40 / 41..80, exact original order), shfl_xor(1)
// combine, __logf — bit-identical to all prior rounds. LDS reads stride
// 81 floats == bank stride 17 (coprime 32) -> <=2-way aliasing (free).
// Block 0 also zeroes the small accumulator region (consumers are in later
// kernels; the kernel boundary orders it).
__global__ __launch_bounds__(256) void k_lse(
        const float* __restrict__ conf, float* __restrict__ lse,
        u32* __restrict__ zws, int nz, long long BP) {
    __shared__ float s[LSE_ROWS * 81];
    const int bid = blockIdx.x;
    if (bid == 0)
        for (int i = threadIdx.x; i < nz; i += 256) zws[i] = 0;
    const long long r0 = (long long)bid * LSE_ROWS;
    const int w = threadIdx.x >> 6;
    const int lane = threadIdx.x & 63;
    const char* gbase = (const char*)(conf + r0 * 81);   // 41472B tile, 16B-aligned

    if (r0 + LSE_ROWS <= BP) {
        // fast path: full tile via global_load_lds
        for (int i = w * 10; i < w * 10 + 10; i++)
            gload16(gbase + (size_t)i * 1024 + lane * 16, (char*)s + i * 1024);
        if (w == 0) {
            gload4(gbase + 40960 + lane * 4, (char*)s + 40960);
            gload4(gbase + 41216 + lane * 4, (char*)s + 41216);
        }
        asm volatile("s_waitcnt vmcnt(0)" ::: "memory");
    } else {
        // partial tail tile (not hit at the bench shape): scalar staging
        int nfl = (int)(BP - r0) * 81;
        const float* src = (const float*)gbase;
        for (int i = threadIdx.x; i < nfl; i += 256) s[i] = src[i];
    }
    __syncthreads();

    const int row = threadIdx.x >> 1;
    const int half = threadIdx.x & 1;
    if (r0 + row < BP) {
        const float* rp = s + row * 81;
        const int c0 = half * 41;
        const int cn = half ? 40 : 41;
        float sum = 0.f;
        for (int j = 0; j < cn; j++) sum += __expf(rp[c0 + j]);
        sum += __shfl_xor(sum, 1);
        if (half == 0) lse[r0 + row] = __logf(sum);
    }
}

// ---------------------------------------------------------------- K1b: match + tbest
// [0, SB)      : per-prior best truth (identical math to prior rounds).
// [SB, SB+TB)  : per-truth best prior (identical math to prior rounds).
__global__ __launch_bounds__(256) void k_spec(
        const float* __restrict__ targets, const float* __restrict__ priors,
        float* __restrict__ bto, int* __restrict__ bti, ull* __restrict__ tbest,
        int P, int O, int S, int SB, int npairs) {
    const int bid = blockIdx.x;
    __shared__ float4 tbox[128];
    __shared__ float tarea[128];
    if (bid < SB) {
        // ---- per-prior best truth (match) ----
        const int b = bid / S, seg = bid % S;
        const float* trow = targets + (size_t)b * O * 5;
        for (int o = threadIdx.x; o < O; o += 256) {
            float x1 = trow[o * 5 + 0], y1 = trow[o * 5 + 1];
            float x2 = trow[o * 5 + 2], y2 = trow[o * 5 + 3];
            tbox[o] = make_float4(x1, y1, x2, y2);
            tarea[o] = (x2 - x1) * (y2 - y1);
        }
        __syncthreads();
        const int p0 = seg * (256 * PPT);
        float px1[PPT], py1[PPT], px2[PPT], py2[PPT], pa[PPT];
        float bestv[PPT]; int besto[PPT]; int pidx[PPT];
#pragma unroll
        for (int j = 0; j < PPT; j++) {
            int p = p0 + (int)threadIdx.x + j * 256;
            pidx[j] = p; bestv[j] = -1.f; besto[j] = 0;
            if (p < P) {
                float4 pr = ((const float4*)priors)[p];
                px1[j] = pr.x - pr.z / 2.f;
                py1[j] = pr.y - pr.w / 2.f;
                px2[j] = pr.x + pr.z / 2.f;
                py2[j] = pr.y + pr.w / 2.f;
                pa[j] = (px2[j] - px1[j]) * (py2[j] - py1[j]);
            } else {
                px1[j] = 2.f; py1[j] = 2.f; px2[j] = 2.f; py2[j] = 2.f; pa[j] = 1.f;
            }
        }
        for (int o = 0; o < O; o++) {
            float4 t = tbox[o];
            float ta = tarea[o];
#pragma unroll
            for (int j = 0; j < PPT; j++) {
                float lx = fmaxf(t.x, px1[j]), ly = fmaxf(t.y, py1[j]);
                float rx = fminf(t.z, px2[j]), ry = fminf(t.w, py2[j]);
                float wx = fmaxf(rx - lx, 0.f), wy = fmaxf(ry - ly, 0.f);
                float inter = wx * wy;
                float iou = 0.f;
                if (inter > 0.f) iou = inter / (ta + pa[j] - inter);
                if (iou > bestv[j]) { bestv[j] = iou; besto[j] = o; }
            }
        }
#pragma unroll
        for (int j = 0; j < PPT; j++) {
            if (pidx[j] < P) {
                bto[(size_t)b * P + pidx[j]] = bestv[j];
                bti[(size_t)b * P + pidx[j]] = besto[j];
            }
        }
    } else {
        // ---- per-truth best prior (tbest) ----
        // one wave per 2 truths; packed key (iou_bits<<32)|~p: max -> (max iou,
        // first index on ties); all-zero row -> ~p maximal at p=0 == jnp.argmax.
        int g = (bid - SB) * 4 + ((int)threadIdx.x >> 6);
        int lane = threadIdx.x & 63;
        if (g >= npairs) return;
        int OP = (O + 1) >> 1;
        int b = g / OP;
        int o0 = (g % OP) * 2;
        const float* trow = targets + ((size_t)b * O + o0) * 5;
        float ax1 = trow[0], ay1 = trow[1], ax2 = trow[2], ay2 = trow[3];
        float ta0 = (ax2 - ax1) * (ay2 - ay1);
        bool has1 = (o0 + 1) < O;
        float cx1 = 0, cy1 = 0, cx2 = 0, cy2 = 0, ta1 = 1.f;
        if (has1) {
            cx1 = trow[5]; cy1 = trow[6]; cx2 = trow[7]; cy2 = trow[8];
            ta1 = (cx2 - cx1) * (cy2 - cy1);
        }
        ull k0v = 0, k1v = 0;
        for (int p = lane; p < P; p += 64) {
            float4 pr = ((const float4*)priors)[p];
            float bx1 = pr.x - pr.z / 2.f;
            float by1 = pr.y - pr.w / 2.f;
            float bx2 = pr.x + pr.z / 2.f;
            float by2 = pr.y + pr.w / 2.f;
            float pa = (bx2 - bx1) * (by2 - by1);
            u32 np = ~(u32)p;
            {
                float lx = fmaxf(ax1, bx1), ly = fmaxf(ay1, by1);
                float rx = fminf(ax2, bx2), ry = fminf(ay2, by2);
                float wx = fmaxf(rx - lx, 0.f), wy = fmaxf(ry - ly, 0.f);
                float inter = wx * wy;
                float iou = 0.f;
                if (inter > 0.f) iou = inter / (ta0 + pa - inter);
                ull key = ((ull)__float_as_uint(iou) << 32) | np;
                if (key > k0v) k0v = key;
            }
            if (has1) {
                float lx = fmaxf(cx1, bx1), ly = fmaxf(cy1, by1);
                float rx = fminf(cx2, bx2), ry = fminf(cy2, by2);
                float wx = fmaxf(rx - lx, 0.f), wy = fmaxf(ry - ly, 0.f);
                float inter = wx * wy;
                float iou = 0.f;
                if (inter > 0.f) iou = inter / (ta1 + pa - inter);
                ull key = ((ull)__float_as_uint(iou) << 32) | np;
                if (key > k1v) k1v = key;
            }
        }
        for (int off = 32; off; off >>= 1) {
            ull a = __shfl_xor(k0v, off); if (a > k0v) k0v = a;
            ull d = __shfl_xor(k1v, off); if (d > k1v) k1v = d;
        }
        if (lane == 0) {
            tbest[(size_t)b * O + o0] = k0v;
            if (has1) tbest[(size_t)b * O + o0 + 1] = k1v;
        }
    }
}

// ---------------------------------------------------------------- K2: force + encode + smooth-L1 + CE finalize
// Forcing via per-block LDS override table (atomicMax by truth index == numpy
// last-wins scatter); conf_t overwrites bti in place. CE finalize is a single
// gather: ce = lse - conf[row][t] (conf row L2/L3-resident after K1's stream;
// identical bits to the LDS-staged subtraction). ce overwrites bto in place —
// same-thread read-then-write within one iteration.
__global__ __launch_bounds__(256) void k_encode_ce(
        const float* __restrict__ targets, const float* __restrict__ priors,
        const float* __restrict__ loc_data, const float* __restrict__ conf,
        const ull* __restrict__ tbest, const float* __restrict__ lse,
        float* __restrict__ F,          // in: bto, out: ce
        int* __restrict__ conf_t,       // in: bti, out: conf label
        int* __restrict__ num_pos, float* __restrict__ loss_l,
        int P, int O) {
    const int b = blockIdx.y, seg = blockIdx.x;
    __shared__ float tr[64 * 5];
    __shared__ int ov[ENC_SEG];
    __shared__ float redf[4]; __shared__ int redi[4];
    const int p0 = seg * ENC_SEG;
    const int p1 = min(p0 + ENC_SEG, P);
    const int nprior = p1 - p0;
    const float* trow = targets + (size_t)b * O * 5;
    for (int i = threadIdx.x; i < O * 5; i += 256) tr[i] = trow[i];
    for (int i = threadIdx.x; i < nprior; i += 256) ov[i] = -1;
    __syncthreads();
    if ((int)threadIdx.x < O) {
        ull tb = tbest[(size_t)b * O + threadIdx.x];
        u32 p = ~(u32)(tb & 0xFFFFFFFFULL);
        if (p >= (u32)P) p = 0;
        if ((int)p >= p0 && (int)p < p1) atomicMax(&ov[p - p0], (int)threadIdx.x);
    }
    __syncthreads();
    float ll = 0.f; int cnt = 0;
    for (int p = p0 + (int)threadIdx.x; p < p1; p += 256) {
        size_t idx = (size_t)b * P + p;
        int o = conf_t[idx];
        int ovv = ov[p - p0];
        bool forced = ovv >= 0;
        if (forced) o = ovv;
        float ovl = F[idx];
        int cv = (!forced && ovl < THRESH) ? 0 : ((int)tr[o * 5 + 4] + 1);
        conf_t[idx] = cv;
        if (cv > 0) {
            cnt++;
            float4 pr = ((const float4*)priors)[p];
            float mx1 = tr[o * 5], my1 = tr[o * 5 + 1];
            float mx2 = tr[o * 5 + 2], my2 = tr[o * 5 + 3];
            float gx = ((mx1 + mx2) / 2.f - pr.x) / (0.1f * pr.z);
            float gy = ((my1 + my2) / 2.f - pr.y) / (0.1f * pr.w);
            float gw = logf((mx2 - mx1) / pr.z) / 0.2f;
            float gh = logf((my2 - my1) / pr.w) / 0.2f;
            float4 ld = ((const float4*)loc_data)[idx];
            ll += sl1(ld.x - gx) + sl1(ld.y - gy) + sl1(ld.z - gw) + sl1(ld.w - gh);
        }
        // CE finalize: lse - conf[row][target]
        float tv = conf[idx * 81 + cv];
        F[idx] = lse[idx] - tv;
    }
    for (int off = 32; off; off >>= 1) {
        ll += __shfl_down(ll, off);
        cnt += __shfl_down(cnt, off);
    }
    int w = threadIdx.x >> 6;
    if ((threadIdx.x & 63) == 0) { redf[w] = ll; redi[w] = cnt; }
    __syncthreads();
    if (threadIdx.x == 0) {
        float l = 0; int c = 0;
        for (int i = 0; i < 4; i++) { l += redf[i]; c += redi[i]; }
        if (c) atomicAdd(&num_pos[b], c);
        atomicAdd(&loss_l[b], l);
    }
}

// ---------------------------------------------------------------- K3: radix top-k select + final
// Unchanged.
__global__ __launch_bounds__(SEL_T) void k_select(
        const float* __restrict__ ce, const int* __restrict__ conf_t,
        const int* __restrict__ num_pos, const float* __restrict__ loss_l,
        float* __restrict__ acc, u32* __restrict__ ticket,
        float* __restrict__ out, int P, int B) {
    extern __shared__ u32 sk[];
    __shared__ u32 whist[SEL_T / 64][16];
    __shared__ u32 hist[16];
    __shared__ float redf[SEL_T / 64]; __shared__ u32 redu[SEL_T / 64];
    __shared__ u32 sh_pval; __shared__ int sh_rem;
    const int b = blockIdx.x;
    const size_t base = (size_t)b * P;
    const int lane = threadIdx.x & 63;
    const int w = threadIdx.x >> 6;
    const int NW = SEL_T / 64;

    float ps = 0.f;
    for (int p = threadIdx.x; p < P; p += SEL_T) {
        int c = conf_t[base + p];
        float v = ce[base + p];
        u32 key;
        if (c > 0) { ps += v; key = 0u; }
        else key = __float_as_uint(fmaxf(v, 0.f));
        sk[p] = key;
    }
    for (int off = 32; off; off >>= 1) ps += __shfl_down(ps, off);
    if (lane == 0) redf[w] = ps;
    __syncthreads();
    float pos_sum = 0.f;
    if (threadIdx.x == 0) {
        for (int i = 0; i < NW; i++) pos_sum += redf[i];
    }

    const int np = num_pos[b];
    const int k = min(3 * np, P - 1);
    u32 pval = 0, pmask = 0; int rem = k;
    if (k > 0) {
        for (int shift = 28; shift >= 0; shift -= 4) {
            __syncthreads();
            ull a0 = 0, a1 = 0;
            for (int p = threadIdx.x; p < P; p += SEL_T) {
                u32 key = sk[p];
                if ((key & pmask) == pval) {
                    u32 dig = (key >> shift) & 15u;
                    ull inc = 1ull << ((dig & 7u) * 8u);
                    if (dig < 8u) a0 += inc; else a1 += inc;
                }
            }
            const ull M = 0x00FF00FF00FF00FFull;
            ull e0 = a0 & M, e1 = (a0 >> 8) & M, e2 = a1 & M, e3 = (a1 >> 8) & M;
            for (int off = 32; off; off >>= 1) {
                e0 += __shfl_xor(e0, off);
                e1 += __shfl_xor(e1, off);
                e2 += __shfl_xor(e2, off);
                e3 += __shfl_xor(e3, off);
            }
            if (lane == 0) {
#pragma unroll
                for (int j = 0; j < 4; j++) {
                    whist[w][2 * j]     = (u32)((e0 >> (16 * j)) & 0xFFFF);
                    whist[w][2 * j + 1] = (u32)((e1 >> (16 * j)) & 0xFFFF);
                    whist[w][8 + 2 * j]     = (u32)((e2 >> (16 * j)) & 0xFFFF);
                    whist[w][8 + 2 * j + 1] = (u32)((e3 >> (16 * j)) & 0xFFFF);
                }
            }
            __syncthreads();
            if (threadIdx.x < 16) {
                u32 h = 0;
                for (int i = 0; i < NW; i++) h += whist[i][threadIdx.x];
                hist[threadIdx.x] = h;
            }
            __syncthreads();
            if (threadIdx.x == 0) {
                u32 accu = 0; int d = 15;
                for (; d > 0; d--) {
                    u32 h = hist[d];
                    if (accu + h >= (u32)rem) break;
                    accu += h;
                }
                sh_pval = pval | ((u32)d << shift);
                sh_rem = rem - (int)accu;
            }
            __syncthreads();
            pval = sh_pval; rem = sh_rem; pmask |= (0xFu << shift);
        }
    }

    float sgt = 0.f; u32 cgt = 0;
    if (k > 0) {
        for (int p = threadIdx.x; p < P; p += SEL_T) {
            u32 key = sk[p];
            if (key > pval) { sgt += __uint_as_float(key); cgt++; }
        }
    }
    for (int off = 32; off; off >>= 1) {
        sgt += __shfl_down(sgt, off);
        cgt += __shfl_down(cgt, off);
    }
    __syncthreads();
    if (lane == 0) { redf[w] = sgt; redu[w] = cgt; }
    __syncthreads();
    if (threadIdx.x == 0) {
        float s = 0.f; u32 c = 0;
        for (int i = 0; i < NW; i++) { s += redf[i]; c += redu[i]; }
        float t = __uint_as_float(pval);
        float lc_b = pos_sum + ((k > 0) ? (s + (float)(k - (int)c) * t) : 0.f);
        atomicAdd(&acc[0], (float)np);
        atomicAdd(&acc[1], loss_l[b]);
        atomicAdd(&acc[2], lc_b);
        __threadfence();
        u32 tk = atomicAdd(ticket, 1u);
        if (tk == (u32)(B - 1)) {
            float n  = atomicAdd(&acc[0], 0.f);
            float ll = atomicAdd(&acc[1], 0.f);
            float lc = atomicAdd(&acc[2], 0.f);
            out[0] = ll / n;
            out[1] = lc / n;
        }
    }
}

// ---------------------------------------------------------------- launch

extern "C" void kernel_launch(void* const* d_in, const int* in_sizes, int n_in,
                              void* d_out, int out_size, void* d_ws, size_t ws_size,
                              hipStream_t stream) {
    const float* loc     = (const float*)d_in[0];
    const float* conf    = (const float*)d_in[1];
    const float* targets = (const float*)d_in[2];
    const float* priors  = (const float*)d_in[3];

    const int P = in_sizes[3] / 4;
    const int B = in_sizes[0] / (P * 4);
    const int O = in_sizes[2] / (B * 5);
    const long long BP = (long long)B * P;

    char* ws = (char*)d_ws;
    size_t off = 0;
    int*   num_pos = (int*)(ws + off);   off += (size_t)B * sizeof(int);
    float* loss_l  = (float*)(ws + off); off += (size_t)B * sizeof(float);
    float* acc     = (float*)(ws + off); off += 4 * sizeof(float);
    u32*   ticket  = (u32*)(ws + off);   off += sizeof(u32);
    const int zwords = (int)(off >> 2);  // zero-init region, cleared by k_lse
    off = (off + 7) & ~(size_t)7;        // align 8 for tbest
    ull*   tbest   = (ull*)(ws + off);   off += (size_t)B * O * sizeof(ull);
    float* F       = (float*)(ws + off); off += (size_t)BP * sizeof(float); // bto -> ce
    int*   I       = (int*)(ws + off);   off += (size_t)BP * sizeof(int);   // bti -> conf_t
    float* L       = (float*)(ws + off); off += (size_t)BP * sizeof(float); // lse

    const int CB = (int)((BP + LSE_ROWS - 1) / LSE_ROWS);
    k_lse<<<CB, 256, 0, stream>>>(conf, L, (u32*)ws, zwords, BP);

    const int SEG = 256 * PPT;
    const int S = (P + SEG - 1) / SEG;
    const int SB = S * B;
    const int npairs = B * ((O + 1) / 2);
    const int TB = (npairs + 3) / 4;
    k_spec<<<SB + TB, 256, 0, stream>>>(targets, priors, F, I, tbest, P, O, S, SB, npairs);

    const int S2 = (P + ENC_SEG - 1) / ENC_SEG;
    k_encode_ce<<<dim3(S2, B), 256, 0, stream>>>(targets, priors, loc, conf, tbest, L,
                                                 F, I, num_pos, loss_l, P, O);

    k_select<<<B, SEL_T, (size_t)P * sizeof(u32), stream>>>(F, I, num_pos, loss_l,
                                                            acc, ticket, (float*)d_out, P, B);
}

// Round 5
// 359.672 us; speedup vs baseline: 1.0383x; 1.0383x over previous
//
#include <hip/hip_runtime.h>
#include <float.h>

// Disable FP contraction file-wide: IoU/encode/threshold compares must match
// numpy bit patterns; none of the hot loops are FMA-throughput-bound.
#pragma clang fp contract(off)

typedef unsigned long long ull;
typedef unsigned int u32;

#define THRESH 0.5f
#define PPT 4          // priors per thread in match phase
#define SEL_T 512      // threads in k_select
#define ENC_SEG 1024   // priors per k_encode_ce block
#define LSE_ROWS 128   // conf rows per LSE block (tile = 128*324B = 41472B)

// ---------------------------------------------------------------- helpers

__device__ __forceinline__ float sl1(float d) {
    float a = fabsf(d);
    return (a < 1.f) ? 0.5f * d * d : a - 0.5f;
}

__device__ __forceinline__ void gload16(const void* g, void* l) {
    __builtin_amdgcn_global_load_lds(
        (const __attribute__((address_space(1))) void*)g,
        (__attribute__((address_space(3))) void*)l, 16, 0, 0);
}
__device__ __forceinline__ void gload4(const void* g, void* l) {
    __builtin_amdgcn_global_load_lds(
        (const __attribute__((address_space(1))) void*)g,
        (__attribute__((address_space(3))) void*)l, 4, 0, 0);
}

// ---------------------------------------------------------------- K1: fused prep
// LSE blocks (coalesced global_load_lds staging) and spec blocks (match/tbest,
// VALU-heavy) PROPORTIONALLY INTERLEAVED across one grid so every CU
// co-schedules memory-streaming and VALU-heavy waves (R3's overlap + R4's
// coalesced staging). Spec block k sits at bid where floor(bid*SPEC/G)
// increments; LSE blocks fill the rest.
//   LSE   : 128-row (41472B) conf tile staged via 40 x gload16-KB chunks +
//           2 x 256B tails; then 2 threads/row serial-half sums (elems
//           0..40 / 41..80, exact original order), shfl_xor(1) combine,
//           __logf — bit-identical to all prior rounds. LDS read stride
//           81 floats == bank stride 17 (coprime 32) -> <=2-way (free).
//   match : per-prior best truth (identical math to prior rounds).
//   tbest : per-truth best prior (identical math to prior rounds).
// LDS overlay: spec carves tbox/tarea from the same buffer (branches are
// disjoint; one static 41.5KB allocation, 3 blocks/CU).
// Block 0 zeroes the small accumulator region (consumed by later kernels;
// the kernel boundary orders it).
__global__ __launch_bounds__(256) void k_prep(
        const float* __restrict__ targets, const float* __restrict__ priors,
        const float* __restrict__ conf,
        float* __restrict__ bto, int* __restrict__ bti, ull* __restrict__ tbest,
        float* __restrict__ lse,
        u32* __restrict__ zws, int nz,
        int P, int O, int S, int SB, int SPEC, int G, int npairs, long long BP) {
    __shared__ __align__(16) float smem[LSE_ROWS * 81];
    const int bid = blockIdx.x;
    if (bid == 0)
        for (int i = threadIdx.x; i < nz; i += 256) zws[i] = 0;

    long long t0 = (long long)bid * SPEC;
    int k0 = (int)(t0 / G);                       // # spec blocks before bid
    bool is_spec = (int)((t0 + SPEC) / G) > k0;

    if (!is_spec) {
        // ---- LSE block: coalesced gload_lds staging ----
        const int lb = bid - k0;
        const long long r0 = (long long)lb * LSE_ROWS;
        const int w = threadIdx.x >> 6;
        const int lane = threadIdx.x & 63;
        const char* gbase = (const char*)(conf + r0 * 81);  // 41472B, 16B-aligned

        if (r0 + LSE_ROWS <= BP) {
            for (int i = w * 10; i < w * 10 + 10; i++)
                gload16(gbase + (size_t)i * 1024 + lane * 16, (char*)smem + i * 1024);
            if (w == 0) {
                gload4(gbase + 40960 + lane * 4, (char*)smem + 40960);
                gload4(gbase + 41216 + lane * 4, (char*)smem + 41216);
            }
            asm volatile("s_waitcnt vmcnt(0)" ::: "memory");
        } else {
            int nfl = (int)(BP - r0) * 81;
            const float* src = (const float*)gbase;
            for (int i = threadIdx.x; i < nfl; i += 256) smem[i] = src[i];
        }
        __syncthreads();

        const int row = threadIdx.x >> 1;
        const int half = threadIdx.x & 1;
        if (r0 + row < BP) {
            const float* rp = smem + row * 81;
            const int c0 = half * 41;
            const int cn = half ? 40 : 41;
            float sum = 0.f;
            for (int j = 0; j < cn; j++) sum += __expf(rp[c0 + j]);
            sum += __shfl_xor(sum, 1);
            if (half == 0) lse[r0 + row] = __logf(sum);
        }
        return;
    }

    const int sidx = k0;   // block-uniform spec index
    if (sidx < SB) {
        // ---- per-prior best truth (match) ----
        float4* tbox = (float4*)smem;                 // 128 * 16B
        float*  tarea = smem + 512;                   // 128 * 4B
        const int b = sidx / S, seg = sidx % S;
        const float* trow = targets + (size_t)b * O * 5;
        for (int o = threadIdx.x; o < O; o += 256) {
            float x1 = trow[o * 5 + 0], y1 = trow[o * 5 + 1];
            float x2 = trow[o * 5 + 2], y2 = trow[o * 5 + 3];
            tbox[o] = make_float4(x1, y1, x2, y2);
            tarea[o] = (x2 - x1) * (y2 - y1);
        }
        __syncthreads();
        const int p0 = seg * (256 * PPT);
        float px1[PPT], py1[PPT], px2[PPT], py2[PPT], pa[PPT];
        float bestv[PPT]; int besto[PPT]; int pidx[PPT];
#pragma unroll
        for (int j = 0; j < PPT; j++) {
            int p = p0 + (int)threadIdx.x + j * 256;
            pidx[j] = p; bestv[j] = -1.f; besto[j] = 0;
            if (p < P) {
                float4 pr = ((const float4*)priors)[p];
                px1[j] = pr.x - pr.z / 2.f;
                py1[j] = pr.y - pr.w / 2.f;
                px2[j] = pr.x + pr.z / 2.f;
                py2[j] = pr.y + pr.w / 2.f;
                pa[j] = (px2[j] - px1[j]) * (py2[j] - py1[j]);
            } else {
                px1[j] = 2.f; py1[j] = 2.f; px2[j] = 2.f; py2[j] = 2.f; pa[j] = 1.f;
            }
        }
        for (int o = 0; o < O; o++) {
            float4 t = tbox[o];
            float ta = tarea[o];
#pragma unroll
            for (int j = 0; j < PPT; j++) {
                float lx = fmaxf(t.x, px1[j]), ly = fmaxf(t.y, py1[j]);
                float rx = fminf(t.z, px2[j]), ry = fminf(t.w, py2[j]);
                float wx = fmaxf(rx - lx, 0.f), wy = fmaxf(ry - ly, 0.f);
                float inter = wx * wy;
                float iou = 0.f;
                if (inter > 0.f) iou = inter / (ta + pa[j] - inter);
                if (iou > bestv[j]) { bestv[j] = iou; besto[j] = o; }
            }
        }
#pragma unroll
        for (int j = 0; j < PPT; j++) {
            if (pidx[j] < P) {
                bto[(size_t)b * P + pidx[j]] = bestv[j];
                bti[(size_t)b * P + pidx[j]] = besto[j];
            }
        }
    } else {
        // ---- per-truth best prior (tbest) ----
        // one wave per 2 truths; packed key (iou_bits<<32)|~p: max -> (max iou,
        // first index on ties); all-zero row -> ~p maximal at p=0 == jnp.argmax.
        int g = (sidx - SB) * 4 + ((int)threadIdx.x >> 6);
        int lane = threadIdx.x & 63;
        if (g >= npairs) return;
        int OP = (O + 1) >> 1;
        int b = g / OP;
        int o0 = (g % OP) * 2;
        const float* trow = targets + ((size_t)b * O + o0) * 5;
        float ax1 = trow[0], ay1 = trow[1], ax2 = trow[2], ay2 = trow[3];
        float ta0 = (ax2 - ax1) * (ay2 - ay1);
        bool has1 = (o0 + 1) < O;
        float cx1 = 0, cy1 = 0, cx2 = 0, cy2 = 0, ta1 = 1.f;
        if (has1) {
            cx1 = trow[5]; cy1 = trow[6]; cx2 = trow[7]; cy2 = trow[8];
            ta1 = (cx2 - cx1) * (cy2 - cy1);
        }
        ull k0v = 0, k1v = 0;
        for (int p = lane; p < P; p += 64) {
            float4 pr = ((const float4*)priors)[p];
            float bx1 = pr.x - pr.z / 2.f;
            float by1 = pr.y - pr.w / 2.f;
            float bx2 = pr.x + pr.z / 2.f;
            float by2 = pr.y + pr.w / 2.f;
            float pa = (bx2 - bx1) * (by2 - by1);
            u32 np = ~(u32)p;
            {
                float lx = fmaxf(ax1, bx1), ly = fmaxf(ay1, by1);
                float rx = fminf(ax2, bx2), ry = fminf(ay2, by2);
                float wx = fmaxf(rx - lx, 0.f), wy = fmaxf(ry - ly, 0.f);
                float inter = wx * wy;
                float iou = 0.f;
                if (inter > 0.f) iou = inter / (ta0 + pa - inter);
                ull key = ((ull)__float_as_uint(iou) << 32) | np;
                if (key > k0v) k0v = key;
            }
            if (has1) {
                float lx = fmaxf(cx1, bx1), ly = fmaxf(cy1, by1);
                float rx = fminf(cx2, bx2), ry = fminf(cy2, by2);
                float wx = fmaxf(rx - lx, 0.f), wy = fmaxf(ry - ly, 0.f);
                float inter = wx * wy;
                float iou = 0.f;
                if (inter > 0.f) iou = inter / (ta1 + pa - inter);
                ull key = ((ull)__float_as_uint(iou) << 32) | np;
                if (key > k1v) k1v = key;
            }
        }
        for (int off = 32; off; off >>= 1) {
            ull a = __shfl_xor(k0v, off); if (a > k0v) k0v = a;
            ull d = __shfl_xor(k1v, off); if (d > k1v) k1v = d;
        }
        if (lane == 0) {
            tbest[(size_t)b * O + o0] = k0v;
            if (has1) tbest[(size_t)b * O + o0 + 1] = k1v;
        }
    }
}

// ---------------------------------------------------------------- K2: force + encode + smooth-L1 + CE finalize
// Forcing via per-block LDS override table (atomicMax by truth index == numpy
// last-wins scatter); conf_t overwrites bti in place. CE finalize is a single
// gather: ce = lse - conf[row][t] (conf row L2/L3-resident after K1's stream;
// identical bits to the LDS-staged subtraction). ce overwrites bto in place —
// same-thread read-then-write within one iteration.
__global__ __launch_bounds__(256) void k_encode_ce(
        const float* __restrict__ targets, const float* __restrict__ priors,
        const float* __restrict__ loc_data, const float* __restrict__ conf,
        const ull* __restrict__ tbest, const float* __restrict__ lse,
        float* __restrict__ F,          // in: bto, out: ce
        int* __restrict__ conf_t,       // in: bti, out: conf label
        int* __restrict__ num_pos, float* __restrict__ loss_l,
        int P, int O) {
    const int b = blockIdx.y, seg = blockIdx.x;
    __shared__ float tr[64 * 5];
    __shared__ int ov[ENC_SEG];
    __shared__ float redf[4]; __shared__ int redi[4];
    const int p0 = seg * ENC_SEG;
    const int p1 = min(p0 + ENC_SEG, P);
    const int nprior = p1 - p0;
    const float* trow = targets + (size_t)b * O * 5;
    for (int i = threadIdx.x; i < O * 5; i += 256) tr[i] = trow[i];
    for (int i = threadIdx.x; i < nprior; i += 256) ov[i] = -1;
    __syncthreads();
    if ((int)threadIdx.x < O) {
        ull tb = tbest[(size_t)b * O + threadIdx.x];
        u32 p = ~(u32)(tb & 0xFFFFFFFFULL);
        if (p >= (u32)P) p = 0;
        if ((int)p >= p0 && (int)p < p1) atomicMax(&ov[p - p0], (int)threadIdx.x);
    }
    __syncthreads();
    float ll = 0.f; int cnt = 0;
    for (int p = p0 + (int)threadIdx.x; p < p1; p += 256) {
        size_t idx = (size_t)b * P + p;
        int o = conf_t[idx];
        int ovv = ov[p - p0];
        bool forced = ovv >= 0;
        if (forced) o = ovv;
        float ovl = F[idx];
        int cv = (!forced && ovl < THRESH) ? 0 : ((int)tr[o * 5 + 4] + 1);
        conf_t[idx] = cv;
        if (cv > 0) {
            cnt++;
            float4 pr = ((const float4*)priors)[p];
            float mx1 = tr[o * 5], my1 = tr[o * 5 + 1];
            float mx2 = tr[o * 5 + 2], my2 = tr[o * 5 + 3];
            float gx = ((mx1 + mx2) / 2.f - pr.x) / (0.1f * pr.z);
            float gy = ((my1 + my2) / 2.f - pr.y) / (0.1f * pr.w);
            float gw = logf((mx2 - mx1) / pr.z) / 0.2f;
            float gh = logf((my2 - my1) / pr.w) / 0.2f;
            float4 ld = ((const float4*)loc_data)[idx];
            ll += sl1(ld.x - gx) + sl1(ld.y - gy) + sl1(ld.z - gw) + sl1(ld.w - gh);
        }
        // CE finalize: lse - conf[row][target]
        float tv = conf[idx * 81 + cv];
        F[idx] = lse[idx] - tv;
    }
    for (int off = 32; off; off >>= 1) {
        ll += __shfl_down(ll, off);
        cnt += __shfl_down(cnt, off);
    }
    int w = threadIdx.x >> 6;
    if ((threadIdx.x & 63) == 0) { redf[w] = ll; redi[w] = cnt; }
    __syncthreads();
    if (threadIdx.x == 0) {
        float l = 0; int c = 0;
        for (int i = 0; i < 4; i++) { l += redf[i]; c += redi[i]; }
        if (c) atomicAdd(&num_pos[b], c);
        atomicAdd(&loss_l[b], l);
    }
}

// ---------------------------------------------------------------- K3: radix top-k select + final
// Unchanged.
__global__ __launch_bounds__(SEL_T) void k_select(
        const float* __restrict__ ce, const int* __restrict__ conf_t,
        const int* __restrict__ num_pos, const float* __restrict__ loss_l,
        float* __restrict__ acc, u32* __restrict__ ticket,
        float* __restrict__ out, int P, int B) {
    extern __shared__ u32 sk[];
    __shared__ u32 whist[SEL_T / 64][16];
    __shared__ u32 hist[16];
    __shared__ float redf[SEL_T / 64]; __shared__ u32 redu[SEL_T / 64];
    __shared__ u32 sh_pval; __shared__ int sh_rem;
    const int b = blockIdx.x;
    const size_t base = (size_t)b * P;
    const int lane = threadIdx.x & 63;
    const int w = threadIdx.x >> 6;
    const int NW = SEL_T / 64;

    float ps = 0.f;
    for (int p = threadIdx.x; p < P; p += SEL_T) {
        int c = conf_t[base + p];
        float v = ce[base + p];
        u32 key;
        if (c > 0) { ps += v; key = 0u; }
        else key = __float_as_uint(fmaxf(v, 0.f));
        sk[p] = key;
    }
    for (int off = 32; off; off >>= 1) ps += __shfl_down(ps, off);
    if (lane == 0) redf[w] = ps;
    __syncthreads();
    float pos_sum = 0.f;
    if (threadIdx.x == 0) {
        for (int i = 0; i < NW; i++) pos_sum += redf[i];
    }

    const int np = num_pos[b];
    const int k = min(3 * np, P - 1);
    u32 pval = 0, pmask = 0; int rem = k;
    if (k > 0) {
        for (int shift = 28; shift >= 0; shift -= 4) {
            __syncthreads();
            ull a0 = 0, a1 = 0;
            for (int p = threadIdx.x; p < P; p += SEL_T) {
                u32 key = sk[p];
                if ((key & pmask) == pval) {
                    u32 dig = (key >> shift) & 15u;
                    ull inc = 1ull << ((dig & 7u) * 8u);
                    if (dig < 8u) a0 += inc; else a1 += inc;
                }
            }
            const ull M = 0x00FF00FF00FF00FFull;
            ull e0 = a0 & M, e1 = (a0 >> 8) & M, e2 = a1 & M, e3 = (a1 >> 8) & M;
            for (int off = 32; off; off >>= 1) {
                e0 += __shfl_xor(e0, off);
                e1 += __shfl_xor(e1, off);
                e2 += __shfl_xor(e2, off);
                e3 += __shfl_xor(e3, off);
            }
            if (lane == 0) {
#pragma unroll
                for (int j = 0; j < 4; j++) {
                    whist[w][2 * j]     = (u32)((e0 >> (16 * j)) & 0xFFFF);
                    whist[w][2 * j + 1] = (u32)((e1 >> (16 * j)) & 0xFFFF);
                    whist[w][8 + 2 * j]     = (u32)((e2 >> (16 * j)) & 0xFFFF);
                    whist[w][8 + 2 * j + 1] = (u32)((e3 >> (16 * j)) & 0xFFFF);
                }
            }
            __syncthreads();
            if (threadIdx.x < 16) {
                u32 h = 0;
                for (int i = 0; i < NW; i++) h += whist[i][threadIdx.x];
                hist[threadIdx.x] = h;
            }
            __syncthreads();
            if (threadIdx.x == 0) {
                u32 accu = 0; int d = 15;
                for (; d > 0; d--) {
                    u32 h = hist[d];
                    if (accu + h >= (u32)rem) break;
                    accu += h;
                }
                sh_pval = pval | ((u32)d << shift);
                sh_rem = rem - (int)accu;
            }
            __syncthreads();
            pval = sh_pval; rem = sh_rem; pmask |= (0xFu << shift);
        }
    }

    float sgt = 0.f; u32 cgt = 0;
    if (k > 0) {
        for (int p = threadIdx.x; p < P; p += SEL_T) {
            u32 key = sk[p];
            if (key > pval) { sgt += __uint_as_float(key); cgt++; }
        }
    }
    for (int off = 32; off; off >>= 1) {
        sgt += __shfl_down(sgt, off);
        cgt += __shfl_down(cgt, off);
    }
    __syncthreads();
    if (lane == 0) { redf[w] = sgt; redu[w] = cgt; }
    __syncthreads();
    if (threadIdx.x == 0) {
        float s = 0.f; u32 c = 0;
        for (int i = 0; i < NW; i++) { s += redf[i]; c += redu[i]; }
        float t = __uint_as_float(pval);
        float lc_b = pos_sum + ((k > 0) ? (s + (float)(k - (int)c) * t) : 0.f);
        atomicAdd(&acc[0], (float)np);
        atomicAdd(&acc[1], loss_l[b]);
        atomicAdd(&acc[2], lc_b);
        __threadfence();
        u32 tk = atomicAdd(ticket, 1u);
        if (tk == (u32)(B - 1)) {
            float n  = atomicAdd(&acc[0], 0.f);
            float ll = atomicAdd(&acc[1], 0.f);
            float lc = atomicAdd(&acc[2], 0.f);
            out[0] = ll / n;
            out[1] = lc / n;
        }
    }
}

// ---------------------------------------------------------------- launch

extern "C" void kernel_launch(void* const* d_in, const int* in_sizes, int n_in,
                              void* d_out, int out_size, void* d_ws, size_t ws_size,
                              hipStream_t stream) {
    const float* loc     = (const float*)d_in[0];
    const float* conf    = (const float*)d_in[1];
    const float* targets = (const float*)d_in[2];
    const float* priors  = (const float*)d_in[3];

    const int P = in_sizes[3] / 4;
    const int B = in_sizes[0] / (P * 4);
    const int O = in_sizes[2] / (B * 5);
    const long long BP = (long long)B * P;

    char* ws = (char*)d_ws;
    size_t off = 0;
    int*   num_pos = (int*)(ws + off);   off += (size_t)B * sizeof(int);
    float* loss_l  = (float*)(ws + off); off += (size_t)B * sizeof(float);
    float* acc     = (float*)(ws + off); off += 4 * sizeof(float);
    u32*   ticket  = (u32*)(ws + off);   off += sizeof(u32);
    const int zwords = (int)(off >> 2);  // zero-init region, cleared by k_prep
    off = (off + 7) & ~(size_t)7;        // align 8 for tbest
    ull*   tbest   = (ull*)(ws + off);   off += (size_t)B * O * sizeof(ull);
    float* F       = (float*)(ws + off); off += (size_t)BP * sizeof(float); // bto -> ce
    int*   I       = (int*)(ws + off);   off += (size_t)BP * sizeof(int);   // bti -> conf_t
    float* L       = (float*)(ws + off); off += (size_t)BP * sizeof(float); // lse

    const int SEG = 256 * PPT;
    const int S = (P + SEG - 1) / SEG;
    const int SB = S * B;
    const int npairs = B * ((O + 1) / 2);
    const int TB = (npairs + 3) / 4;
    const int CB = (int)((BP + LSE_ROWS - 1) / LSE_ROWS);
    const int SPEC = SB + TB;
    const int G = CB + SPEC;
    k_prep<<<G, 256, 0, stream>>>(targets, priors, conf, F, I, tbest, L,
                                  (u32*)ws, zwords, P, O, S, SB, SPEC, G, npairs, BP);

    const int S2 = (P + ENC_SEG - 1) / ENC_SEG;
    k_encode_ce<<<dim3(S2, B), 256, 0, stream>>>(targets, priors, loc, conf, tbest, L,
                                                 F, I, num_pos, loss_l, P, O);

    k_select<<<B, SEL_T, (size_t)P * sizeof(u32), stream>>>(F, I, num_pos, loss_l,
                                                            acc, ticket, (float*)d_out, P, B);
}